// Round 7
// baseline (299.133 us; speedup 1.0000x reference)
//
#include <hip/hip_runtime.h>
#include <math.h>

#define D_MODEL 1024
#define D_FF    4096
#define RANK    128
#define M_ROWS  8192

typedef _Float16 f16;
typedef _Float16 f16x8 __attribute__((ext_vector_type(8)));
typedef float    f32x4 __attribute__((ext_vector_type(4)));

#define MFMA16(a, b, c) __builtin_amdgcn_mfma_f32_16x16x32_f16((a), (b), (c), 0, 0, 0)

__device__ __forceinline__ f16x8 ld8(const f16* p) { return *(const f16x8*)p; }

__device__ __forceinline__ f16x8 cvt8(float4 a0, float4 a1) {
    f16x8 r = { (f16)a0.x, (f16)a0.y, (f16)a0.z, (f16)a0.w,
                (f16)a1.x, (f16)a1.y, (f16)a1.z, (f16)a1.w };
    return r;
}

__device__ __forceinline__ float gelu_exact(float v) {
    return 0.5f * v * (1.0f + erff(v * 0.70710678118654752440f));
}

// ---------------------------------------------------------------------------
// Prep (verbatim-proven): convert/transpose/scale weights into ws (f16).
//  w1T[r][d] = cfc_U[d][r]*cfc_S[r]     [128][1024]
//  v1 [f][r] = cfc_V[f][r]              [4096][128]
//  w2T[r][f] = cproj_U[f][r]*cproj_S[r] [128][4096]
//  v2 [d][r] = cproj_V[d][r]            [1024][128]
// ---------------------------------------------------------------------------
__global__ __launch_bounds__(256) void k_prep(
    const float* __restrict__ cfcU, const float* __restrict__ cfcS,
    const float* __restrict__ cfcV, const float* __restrict__ pjU,
    const float* __restrict__ pjS,  const float* __restrict__ pjV,
    f16* __restrict__ w1T, f16* __restrict__ v1,
    f16* __restrict__ w2T, f16* __restrict__ v2)
{
    int i = blockIdx.x * 256 + threadIdx.x;
    if (i < 131072) {
        int r = i >> 10, d = i & 1023;
        w1T[i] = (f16)(cfcU[d * RANK + r] * cfcS[r]);
    } else if (i < 655360) {
        int j = i - 131072;
        v1[j] = (f16)cfcV[j];
    } else if (i < 1179648) {
        int j = i - 655360;
        int r = j >> 12, f = j & 4095;
        w2T[j] = (f16)(pjU[f * RANK + r] * pjS[r]);
    } else if (i < 1310720) {
        int j = i - 1179648;
        v2[j] = (f16)pjV[j];
    }
}

// ---------------------------------------------------------------------------
// Stage 1: t1f[m][r] += x[m][k-quarter] @ w1T^T  (fp32 atomic accumulation).
// 1 wave per block, no LDS, no sync. Grid (512 m-tiles, 4 K-quarters) ->
// 2048 waves = 2/SIMD. t1f zeroed by hipMemsetAsync before launch.
// Body = proven k_t1 MFMA loop, K-sliced; epilogue atomicAdd (device-scope).
// ---------------------------------------------------------------------------
__global__ __launch_bounds__(64) void k_t1(
    const float* __restrict__ x, const f16* __restrict__ w1T,
    float* __restrict__ t1f)
{
    const int lane = threadIdx.x & 63;
    const int m0   = blockIdx.x * 16;
    const int k0   = blockIdx.y * 256;
    const int c    = lane & 15, q = lane >> 4;

    f32x4 acc[8] = {};
    const float* xrow = x + (size_t)(m0 + c) * D_MODEL + k0;

#pragma unroll 2
    for (int kb = 0; kb < 8; ++kb) {
        const float* ap = xrow + kb * 32 + q * 8;
        float4 a0 = *(const float4*)ap;
        float4 a1 = *(const float4*)(ap + 4);
        f16x8 af = cvt8(a0, a1);
#pragma unroll
        for (int nt = 0; nt < 8; ++nt) {
            f16x8 bf = ld8(w1T + (size_t)(nt * 16 + c) * D_MODEL + k0 + kb * 32 + q * 8);
            acc[nt] = MFMA16(af, bf, acc[nt]);
        }
    }
#pragma unroll
    for (int nt = 0; nt < 8; ++nt)
#pragma unroll
        for (int i2 = 0; i2 < 4; ++i2)
            atomicAdd(&t1f[(size_t)(m0 + q * 4 + i2) * RANK + nt * 16 + c],
                      acc[nt][i2]);
}

#define RED_STORE(buf, acc)                                            \
    _Pragma("unroll") for (int rt = 0; rt < 8; ++rt)                   \
    _Pragma("unroll") for (int i2 = 0; i2 < 4; ++i2)                   \
        (buf)[q * 4 + i2][rt * 16 + c] = (acc)[rt][i2];
#define RED_ADD(buf, acc)                                              \
    _Pragma("unroll") for (int rt = 0; rt < 8; ++rt)                   \
    _Pragma("unroll") for (int i2 = 0; i2 < 4; ++i2)                   \
        (acc)[rt][i2] += (buf)[q * 4 + i2][rt * 16 + c];

// ---------------------------------------------------------------------------
// Fused stages 2+3. Inner chunk body VERBATIM R5 (proven). Deltas:
//  - grid (512, 4): split s covers 1024 f (16 chunks); wave wv takes 8 ->
//    4096 waves = 4/SIMD (R5 was grid-limited to 2/SIMD, Occupancy 21.5%).
//  - a2 fragments read from fp32 t1f (cvt on load).
//  - epilogue: proven 2-wave reduce, then wave 0 atomicAdds its fp32 tile
//    into the single t2f buffer (replaces per-split f16 partials; ws fits).
// ---------------------------------------------------------------------------
__global__ __launch_bounds__(128, 4) void k_fused(
    const float* __restrict__ t1f, const f16* __restrict__ v1,
    const float* __restrict__ bfc, const f16* __restrict__ w2T,
    float* __restrict__ t2f)
{
    __shared__ __align__(16) f16 hs[2][16][72];   // per-wave h tile
    __shared__ float red[16][132];                // 2-wave reduction buffer

    const int lane = threadIdx.x & 63;
    const int wv   = threadIdx.x >> 6;
    const int m0   = blockIdx.x * 16;
    const int s    = blockIdx.y;
    const int c    = lane & 15, q = lane >> 4;

    // A2 fragments (t1 rows, fp32 -> f16) — live in regs across the f-loop
    f16x8 a2[4];
#pragma unroll
    for (int kb = 0; kb < 4; ++kb) {
        const float* p = t1f + (size_t)(m0 + c) * RANK + kb * 32 + q * 8;
        a2[kb] = cvt8(*(const float4*)p, *(const float4*)(p + 4));
    }

    f32x4 c3[8] = {};

#pragma unroll 1
    for (int ch = 0; ch < 8; ++ch) {
        const int f0 = s * 1024 + (wv * 8 + ch) * 64;

        // ---- stage 2: batch-load all 16 v1 frags, then 16 MFMAs
        f16x8 bf2[4][4];
#pragma unroll
        for (int nt = 0; nt < 4; ++nt)
#pragma unroll
            for (int kb = 0; kb < 4; ++kb)
                bf2[nt][kb] = ld8(v1 + (size_t)(f0 + nt * 16 + c) * RANK + kb * 32 + q * 8);

        f32x4 c2[4] = {};
#pragma unroll
        for (int nt = 0; nt < 4; ++nt)
#pragma unroll
            for (int kb = 0; kb < 4; ++kb)
                c2[nt] = MFMA16(a2[kb], bf2[nt][kb], c2[nt]);

        // ---- issue stage-3 B frags now (independent of hs; overlaps gelu)
        f16x8 bf3[2][8];
#pragma unroll
        for (int kb2 = 0; kb2 < 2; ++kb2)
#pragma unroll
            for (int rt = 0; rt < 8; ++rt)
                bf3[kb2][rt] = ld8(w2T + (size_t)(rt * 16 + c) * D_FF + f0 + kb2 * 32 + q * 8);

        // ---- bias + exact gelu -> per-wave LDS (C-layout scatter)
#pragma unroll
        for (int nt = 0; nt < 4; ++nt) {
            float b = bfc[f0 + nt * 16 + c];
#pragma unroll
            for (int i2 = 0; i2 < 4; ++i2)
                hs[wv][q * 4 + i2][nt * 16 + c] = (f16)gelu_exact(c2[nt][i2] + b);
        }
        // cross-lane RAW inside the wave: compiler barrier + drain DS queue
        asm volatile("s_waitcnt lgkmcnt(0)" ::: "memory");

        // ---- stage 3: t2 += h @ w2T^T  (A from LDS in A-layout)
#pragma unroll
        for (int kb2 = 0; kb2 < 2; ++kb2) {
            f16x8 a3 = *(const f16x8*)&hs[wv][c][kb2 * 32 + q * 8];
#pragma unroll
            for (int rt = 0; rt < 8; ++rt)
                c3[rt] = MFMA16(a3, bf3[kb2][rt], c3[rt]);
        }
        // keep next iteration's hs writes behind this iteration's reads
        asm volatile("s_waitcnt lgkmcnt(0)" ::: "memory");
    }

    // ---- proven 2-wave reduce, then wave 0 atomic-accumulates into t2f
    if (wv == 1) { RED_STORE(red, c3) }
    __syncthreads();
    if (wv == 0) {
        RED_ADD(red, c3)
#pragma unroll
        for (int rt = 0; rt < 8; ++rt)
#pragma unroll
            for (int i2 = 0; i2 < 4; ++i2)
                atomicAdd(&t2f[(size_t)(m0 + q * 4 + i2) * RANK + rt * 16 + c],
                          c3[rt][i2]);
    }
}

// ---------------------------------------------------------------------------
// Stage 4: out = t2f @ v2^T + bpj, fp32 out. t2f is the fully-summed fp32
// buffer (no partials). Wave tile 16m x 64n, grid (128, 16), 256-thr blocks
// -> 8192 waves = 8/SIMD.
// ---------------------------------------------------------------------------
__global__ __launch_bounds__(256) void k_out(
    const float* __restrict__ t2f, const f16* __restrict__ v2,
    const float* __restrict__ bpj, float* __restrict__ out)
{
    const int lane = threadIdx.x & 63;
    const int wv   = threadIdx.x >> 6;
    const int m0   = blockIdx.x * 64 + wv * 16;
    const int n0   = blockIdx.y * 64;
    const int c    = lane & 15, q = lane >> 4;

    f16x8 a[4];
#pragma unroll
    for (int kb = 0; kb < 4; ++kb) {
        const float* p = t2f + (size_t)(m0 + c) * RANK + kb * 32 + q * 8;
        a[kb] = cvt8(*(const float4*)p, *(const float4*)(p + 4));
    }

    f32x4 acc[4] = {};
#pragma unroll
    for (int nt = 0; nt < 4; ++nt)
#pragma unroll
        for (int kb = 0; kb < 4; ++kb) {
            f16x8 bf = ld8(v2 + (size_t)(n0 + nt * 16 + c) * RANK + kb * 32 + q * 8);
            acc[nt] = MFMA16(a[kb], bf, acc[nt]);
        }

#pragma unroll
    for (int nt = 0; nt < 4; ++nt) {
        float b = bpj[n0 + nt * 16 + c];
#pragma unroll
        for (int i2 = 0; i2 < 4; ++i2)
            out[(size_t)(m0 + q * 4 + i2) * D_MODEL + n0 + nt * 16 + c] =
                acc[nt][i2] + b;
    }
}

extern "C" void kernel_launch(void* const* d_in, const int* in_sizes, int n_in,
                              void* d_out, int out_size, void* d_ws, size_t ws_size,
                              hipStream_t stream) {
    const float* x    = (const float*)d_in[0];
    const float* cfcU = (const float*)d_in[1];
    const float* cfcS = (const float*)d_in[2];
    const float* cfcV = (const float*)d_in[3];
    const float* cfcB = (const float*)d_in[4];
    const float* pjU  = (const float*)d_in[5];
    const float* pjS  = (const float*)d_in[6];
    const float* pjV  = (const float*)d_in[7];
    const float* pjB  = (const float*)d_in[8];
    float* out = (float*)d_out;

    // ws layout: t1f fp32 4MB | t2f fp32 4MB | f16 weights 2.5MB = 10.5MB
    float* t1f = (float*)d_ws;                    // [8192*128] fp32
    float* t2f = t1f + 1048576;                   // [8192*128] fp32
    f16*   w1T = (f16*)(t2f + 1048576);           // [128*1024]
    f16*   v1  = w1T + 131072;                    // [4096*128]
    f16*   w2T = v1  + 524288;                    // [128*4096]
    f16*   v2  = w2T + 524288;                    // [1024*128]

    // zero the two fp32 accumulation buffers (contiguous 8 MB, one call);
    // required every launch (harness re-poisons ws to 0xAA).
    hipMemsetAsync(t1f, 0, 2u * 1048576u * sizeof(float), stream);

    k_prep <<<dim3(5120), 256, 0, stream>>>(cfcU, cfcS, cfcV, pjU, pjS, pjV,
                                            w1T, v1, w2T, v2);
    k_t1   <<<dim3(M_ROWS / 16, 4), 64, 0, stream>>>(x, w1T, t1f);
    k_fused<<<dim3(M_ROWS / 16, 4), 128, 0, stream>>>(t1f, v1, cfcB, w2T, t2f);
    k_out  <<<dim3(M_ROWS / 64, D_MODEL / 64), 256, 0, stream>>>(t2f, v2, pjB, out);
}

// Round 8
// 181.622 us; speedup vs baseline: 1.6470x; 1.6470x over previous
//
#include <hip/hip_runtime.h>
#include <math.h>

#define D_MODEL 1024
#define D_FF    4096
#define RANK    128
#define M_ROWS  8192

typedef _Float16 f16;
typedef _Float16 f16x8 __attribute__((ext_vector_type(8)));
typedef float    f32x4 __attribute__((ext_vector_type(4)));

#define MFMA16(a, b, c) __builtin_amdgcn_mfma_f32_16x16x32_f16((a), (b), (c), 0, 0, 0)

__device__ __forceinline__ f16x8 ld8(const f16* p) { return *(const f16x8*)p; }

__device__ __forceinline__ f16x8 cvt8(float4 a0, float4 a1) {
    f16x8 r = { (f16)a0.x, (f16)a0.y, (f16)a0.z, (f16)a0.w,
                (f16)a1.x, (f16)a1.y, (f16)a1.z, (f16)a1.w };
    return r;
}

__device__ __forceinline__ float gelu_exact(float v) {
    return 0.5f * v * (1.0f + erff(v * 0.70710678118654752440f));
}

// ---------------------------------------------------------------------------
// Prep (verbatim-proven): convert/transpose/scale weights into ws (f16).
//  w1T[r][d]=cfcU[d][r]*cfcS[r] [128][1024] | v1[f][r]=cfcV [4096][128]
//  w2T[r][f]=pjU[f][r]*pjS[r]   [128][4096] | v2[d][r]=pjV  [1024][128]
// ---------------------------------------------------------------------------
__global__ __launch_bounds__(256) void k_prep(
    const float* __restrict__ cfcU, const float* __restrict__ cfcS,
    const float* __restrict__ cfcV, const float* __restrict__ pjU,
    const float* __restrict__ pjS,  const float* __restrict__ pjV,
    f16* __restrict__ w1T, f16* __restrict__ v1,
    f16* __restrict__ w2T, f16* __restrict__ v2)
{
    int i = blockIdx.x * 256 + threadIdx.x;
    if (i < 131072) {
        int r = i >> 10, d = i & 1023;
        w1T[i] = (f16)(cfcU[d * RANK + r] * cfcS[r]);
    } else if (i < 655360) {
        int j = i - 131072;
        v1[j] = (f16)cfcV[j];
    } else if (i < 1179648) {
        int j = i - 655360;
        int r = j >> 12, f = j & 4095;
        w2T[j] = (f16)(pjU[f * RANK + r] * pjS[r]);
    } else if (i < 1310720) {
        int j = i - 1179648;
        v2[j] = (f16)pjV[j];
    }
}

// ---------------------------------------------------------------------------
// Stage 1: t1p[ks][m][r] = x[m][K-half ks] @ w1T^T, f16 partials (no atomics).
// m97-style: x and w1T K-chunks staged into LDS via dense cooperative copies;
// fragments via ds_read. Block 256 thr = 4 waves (wm,wn): wave = 16m x 64n.
// Grid (256 m-tiles of 32, 2 K-halves) = 512 blocks -> 2 blocks/CU.
// ---------------------------------------------------------------------------
__global__ __launch_bounds__(256, 2) void k_t1(
    const float* __restrict__ x, const f16* __restrict__ w1T,
    f16* __restrict__ t1p)
{
    __shared__ __align__(16) float xs[32 * 132];    // [32m][128k fp32, pad 132]
    __shared__ __align__(16) f16   w1s[128 * 136];  // [128n][128k f16, pad 136]

    const int tid  = threadIdx.x;
    const int lane = tid & 63;
    const int wv   = tid >> 6;
    const int wm   = wv & 1, wn = wv >> 1;
    const int m0b  = blockIdx.x * 32;
    const int ks   = blockIdx.y;
    const int k0   = ks * 512;
    const int c    = lane & 15, q = lane >> 4;

    f32x4 acc[4] = {};

#pragma unroll 1
    for (int kc = 0; kc < 4; ++kc) {
        const int kbase = k0 + kc * 128;
        __syncthreads();
        // stage x chunk [32m][128k] fp32 (dense float4 copies)
#pragma unroll
        for (int it = 0; it < 4; ++it) {
            int id = it * 256 + tid;             // < 1024
            int mm = id >> 5, k4 = id & 31;
            *(float4*)&xs[mm * 132 + k4 * 4] =
                *(const float4*)&x[(size_t)(m0b + mm) * D_MODEL + kbase + k4 * 4];
        }
        // stage w1T chunk [128n][128k] f16 (dense f16x8 copies)
#pragma unroll
        for (int it = 0; it < 8; ++it) {
            int id = it * 256 + tid;             // < 2048
            int nn = id >> 4, k8 = id & 15;
            *(f16x8*)&w1s[nn * 136 + k8 * 8] =
                ld8(w1T + (size_t)nn * D_MODEL + kbase + k8 * 8);
        }
        __syncthreads();

#pragma unroll
        for (int kb = 0; kb < 4; ++kb) {
            const float* ap = &xs[(wm * 16 + c) * 132 + kb * 32 + q * 8];
            f16x8 af = cvt8(*(const float4*)ap, *(const float4*)(ap + 4));
#pragma unroll
            for (int nt = 0; nt < 4; ++nt) {
                f16x8 bf = *(const f16x8*)&w1s[(wn * 64 + nt * 16 + c) * 136 + kb * 32 + q * 8];
                acc[nt] = MFMA16(af, bf, acc[nt]);
            }
        }
    }

    f16* o = t1p + (size_t)ks * (M_ROWS * RANK);
#pragma unroll
    for (int nt = 0; nt < 4; ++nt)
#pragma unroll
        for (int i2 = 0; i2 < 4; ++i2)
            o[(size_t)(m0b + wm * 16 + q * 4 + i2) * RANK + wn * 64 + nt * 16 + c] =
                (f16)acc[nt][i2];
}

#define RED_STORE(buf, acc)                                            \
    _Pragma("unroll") for (int rt = 0; rt < 8; ++rt)                   \
    _Pragma("unroll") for (int i2 = 0; i2 < 4; ++i2)                   \
        (buf)[(q * 4 + i2) * 132 + rt * 16 + c] = (acc)[rt][i2];
#define RED_ADD(buf, acc)                                              \
    _Pragma("unroll") for (int rt = 0; rt < 8; ++rt)                   \
    _Pragma("unroll") for (int i2 = 0; i2 < 4; ++i2)                   \
        (acc)[rt][i2] += (buf)[(q * 4 + i2) * 132 + rt * 16 + c];

// ---------------------------------------------------------------------------
// Fused stages 2+3, m97-style. Block 256 thr = 4 waves (wm = wv&1 m-half,
// wf = wv>>1 f-half). Per iter (128 f): stage v1 tile [128f][128r] and w2T
// tile [128r][128f] into LDS (dense copies, __syncthreads pair); each wave:
//   stage2 16 MFMA (its 16m x 64f) -> gelu -> per-wave hs (asm barriers,
//   proven R2/R5) -> stage3 16 MFMA into c3[16m][128r].
// Epilogue: 2-wave reduce over wf (proven R5 pattern), write f16 t2p[split].
// Grid (256 m-tiles of 32, 2 f-splits) = 512 blocks, LDS 78.8 KB -> 2/CU.
// ---------------------------------------------------------------------------
__global__ __launch_bounds__(256, 2) void k_fused(
    const f16* __restrict__ t1p, const f16* __restrict__ v1,
    const float* __restrict__ bfc, const f16* __restrict__ w2T,
    f16* __restrict__ t2p)
{
    __shared__ __align__(16) char smem[78848];
    f16*  v1s = (f16*)smem;                    // [128f][136r]  34816 B
    f16*  w2s = (f16*)(smem + 34816);          // [128r][136f]  34816 B
    f16*  hs  = (f16*)(smem + 69632);          // [4][16][72]    9216 B
    float* red = (float*)smem;                 // epilogue overlay on v1s

    const int tid  = threadIdx.x;
    const int lane = tid & 63;
    const int wv   = tid >> 6;
    const int wm   = wv & 1, wf = wv >> 1;
    const int m0b  = blockIdx.x * 32;
    const int s    = blockIdx.y;
    const int c    = lane & 15, q = lane >> 4;

    // A2 fragments: sum of the two f16 t1 partials, re-rounded to f16
    f16x8 a2[4];
#pragma unroll
    for (int kb = 0; kb < 4; ++kb) {
        const size_t off = (size_t)(m0b + wm * 16 + c) * RANK + kb * 32 + q * 8;
        f16x8 p0 = ld8(t1p + off);
        f16x8 p1 = ld8(t1p + (size_t)(M_ROWS * RANK) + off);
#pragma unroll
        for (int e = 0; e < 8; ++e)
            a2[kb][e] = (f16)((float)p0[e] + (float)p1[e]);
    }

    f32x4 c3[8] = {};

#pragma unroll 1
    for (int it = 0; it < 16; ++it) {
        const int fbase = s * 2048 + it * 128;
        __syncthreads();                       // prev iter's tile reads done
        // stage v1 tile [128f][128r] (contiguous 32 KB in global)
#pragma unroll
        for (int i8 = 0; i8 < 8; ++i8) {
            int id = i8 * 256 + tid;           // < 2048
            int ff = id >> 4, r8 = id & 15;
            *(f16x8*)&v1s[ff * 136 + r8 * 8] =
                ld8(v1 + (size_t)(fbase + ff) * RANK + r8 * 8);
        }
        // stage w2T tile [128r][128f] (rows strided 4096)
#pragma unroll
        for (int i8 = 0; i8 < 8; ++i8) {
            int id = i8 * 256 + tid;           // < 2048
            int rr = id >> 4, f8 = id & 15;
            *(f16x8*)&w2s[rr * 136 + f8 * 8] =
                ld8(w2T + (size_t)rr * D_FF + fbase + f8 * 8);
        }
        __syncthreads();                       // tiles visible

        const int f0 = fbase + wf * 64;        // this wave's 64-f chunk

        // ---- stage 2: h = t1 @ v1^T  (4 f-tiles x K=128), B from LDS
        f32x4 c2[4] = {};
#pragma unroll
        for (int nt = 0; nt < 4; ++nt)
#pragma unroll
            for (int kb = 0; kb < 4; ++kb) {
                f16x8 bf = *(const f16x8*)
                    &v1s[(wf * 64 + nt * 16 + c) * 136 + kb * 32 + q * 8];
                c2[nt] = MFMA16(a2[kb], bf, c2[nt]);
            }

        // ---- bias + exact gelu -> per-wave hs (C-layout scatter)
#pragma unroll
        for (int nt = 0; nt < 4; ++nt) {
            float b = bfc[f0 + nt * 16 + c];
#pragma unroll
            for (int i2 = 0; i2 < 4; ++i2)
                hs[(wv * 16 + q * 4 + i2) * 72 + nt * 16 + c] =
                    (f16)gelu_exact(c2[nt][i2] + b);
        }
        // cross-lane RAW inside the wave (proven R2/R5 guard)
        asm volatile("s_waitcnt lgkmcnt(0)" ::: "memory");

        // ---- stage 3: t2 += h @ w2T^T  (A from hs, B from LDS)
#pragma unroll
        for (int kb2 = 0; kb2 < 2; ++kb2) {
            f16x8 a3 = *(const f16x8*)&hs[(wv * 16 + c) * 72 + kb2 * 32 + q * 8];
#pragma unroll
            for (int rt = 0; rt < 8; ++rt) {
                f16x8 bf = *(const f16x8*)
                    &w2s[(rt * 16 + c) * 136 + wf * 64 + kb2 * 32 + q * 8];
                c3[rt] = MFMA16(a3, bf, c3[rt]);
            }
        }
        asm volatile("s_waitcnt lgkmcnt(0)" ::: "memory");
    }

    // ---- 2-wave reduce over wf (proven pattern), write f16 partial t2p[s]
    __syncthreads();                           // done with v1s before overlay
    if (wf == 1) { RED_STORE(&red[wm * 16 * 132], c3) }
    __syncthreads();
    if (wf == 0) {
        RED_ADD(&red[wm * 16 * 132], c3)
        f16* o = t2p + (size_t)s * (M_ROWS * RANK);
#pragma unroll
        for (int rt = 0; rt < 8; ++rt)
#pragma unroll
            for (int i2 = 0; i2 < 4; ++i2)
                o[(size_t)(m0b + wm * 16 + q * 4 + i2) * RANK + rt * 16 + c] =
                    (f16)c3[rt][i2];
    }
}

// ---------------------------------------------------------------------------
// Stage 4: out = (t2p0+t2p1) @ v2^T + bpj, fp32 out. m97-style single-shot
// v2 tile staging. Block 256 thr = 4 waves (wm,wn): wave = 16m x 128n.
// Grid (256 m-tiles of 32, 4 n-tiles of 256) = 1024 blocks; LDS 69.6 KB.
// ---------------------------------------------------------------------------
__global__ __launch_bounds__(256, 2) void k_out(
    const f16* __restrict__ t2p, const f16* __restrict__ v2,
    const float* __restrict__ bpj, float* __restrict__ out)
{
    __shared__ __align__(16) f16 v2s[256 * 136];   // [256n][128k, pad 136]

    const int tid  = threadIdx.x;
    const int lane = tid & 63;
    const int wv   = tid >> 6;
    const int wm   = wv & 1, wn = wv >> 1;
    const int m0b  = blockIdx.x * 32;
    const int n0b  = blockIdx.y * 256;
    const int c    = lane & 15, q = lane >> 4;

    // stage v2 tile [256n][128k] once (K fully consumed)
#pragma unroll
    for (int i8 = 0; i8 < 16; ++i8) {
        int id = i8 * 256 + tid;               // < 4096
        int nn = id >> 4, k8 = id & 15;
        *(f16x8*)&v2s[nn * 136 + k8 * 8] =
            ld8(v2 + (size_t)(n0b + nn) * RANK + k8 * 8);
    }

    // A-frags: fp32 sum of the two f16 partials
    f16x8 a[4];
#pragma unroll
    for (int kb = 0; kb < 4; ++kb) {
        const size_t off = (size_t)(m0b + wm * 16 + c) * RANK + kb * 32 + q * 8;
        f16x8 p0 = ld8(t2p + off);
        f16x8 p1 = ld8(t2p + (size_t)(M_ROWS * RANK) + off);
#pragma unroll
        for (int e = 0; e < 8; ++e)
            a[kb][e] = (f16)((float)p0[e] + (float)p1[e]);
    }
    __syncthreads();

    f32x4 acc[8] = {};
#pragma unroll
    for (int nt = 0; nt < 8; ++nt)
#pragma unroll
        for (int kb = 0; kb < 4; ++kb) {
            f16x8 bf = *(const f16x8*)
                &v2s[(wn * 128 + nt * 16 + c) * 136 + kb * 32 + q * 8];
            acc[nt] = MFMA16(a[kb], bf, acc[nt]);
        }

#pragma unroll
    for (int nt = 0; nt < 8; ++nt) {
        float b = bpj[n0b + wn * 128 + nt * 16 + c];
#pragma unroll
        for (int i2 = 0; i2 < 4; ++i2)
            out[(size_t)(m0b + wm * 16 + q * 4 + i2) * D_MODEL +
                n0b + wn * 128 + nt * 16 + c] = acc[nt][i2] + b;
    }
}

extern "C" void kernel_launch(void* const* d_in, const int* in_sizes, int n_in,
                              void* d_out, int out_size, void* d_ws, size_t ws_size,
                              hipStream_t stream) {
    const float* x    = (const float*)d_in[0];
    const float* cfcU = (const float*)d_in[1];
    const float* cfcS = (const float*)d_in[2];
    const float* cfcV = (const float*)d_in[3];
    const float* cfcB = (const float*)d_in[4];
    const float* pjU  = (const float*)d_in[5];
    const float* pjS  = (const float*)d_in[6];
    const float* pjV  = (const float*)d_in[7];
    const float* pjB  = (const float*)d_in[8];
    float* out = (float*)d_out;

    // ws layout (f16 elements), 10.5 MB total (12 MB proven safe):
    f16* wsf = (f16*)d_ws;
    f16* t1p = wsf;                 // [2][8192*128]  4 MB
    f16* t2p = wsf + 2097152;       // [2][8192*128]  4 MB
    f16* w1T = wsf + 4194304;       // [128*1024]
    f16* v1  = w1T + 131072;        // [4096*128]
    f16* w2T = v1  + 524288;        // [128*4096]
    f16* v2  = w2T + 524288;        // [1024*128]

    k_prep <<<dim3(5120), 256, 0, stream>>>(cfcU, cfcS, cfcV, pjU, pjS, pjV,
                                            w1T, v1, w2T, v2);
    k_t1   <<<dim3(M_ROWS / 32, 2), 256, 0, stream>>>(x, w1T, t1p);
    k_fused<<<dim3(M_ROWS / 32, 2), 256, 0, stream>>>(t1p, v1, cfcB, w2T, t2p);
    k_out  <<<dim3(M_ROWS / 32, D_MODEL / 256), 256, 0, stream>>>(t2p, v2, pjB, out);
}